// Round 4
// baseline (518.973 us; speedup 1.0000x reference)
//
#include <hip/hip_runtime.h>
#include <math.h>

// Problem constants (fixed by setup_inputs)
#define M_TOK 16384   // B*T
#define DIM   256     // D (=K)
#define VOC   8192    // V (=N)

// GEMM tiling
#define BM 128
#define BN 128
#define BK 32
#define NBLK_N (VOC / BN)   // 64
#define GAP_EPS 0.01f       // rescue trigger; split-bf16 d2 err ~1e-4 << 0.01

typedef unsigned short u16;
typedef unsigned long long u64;
typedef __attribute__((ext_vector_type(8))) __bf16 bf16x8;
typedef __attribute__((ext_vector_type(4))) float f32x4;
typedef __attribute__((ext_vector_type(16))) float f32x16;

// ---- workspace layout (float-element offsets) ------------------------------
#define WS_ESQ      0                     // [8192]
#define WS_FLAGROWS 24576                 // [16384] int
#define WS_CANDV    40960                 // [64][16384] f32
#define WS_CANDI    1089536               // [64][16384] int
#define WS_CANDS    2138112               // [64][16384] f32
#define WS_XHI      3186688               // [16384*256] bf16 (2097152 f32 slots)
#define WS_XLO      5283840
#define WS_EHI      7380992               // [8192*256] bf16 (1048576 slots)
#define WS_ELO      8429568
#define WS_COUNTS   9478144               // [8192]
#define WS_SUMS     9486336               // [8192*256]
#define WS_FLAGCNT  11583488              // [16] int
// rescueBuf [16384] u64 aliases Xhi (dead after mfma_argmin; reduce writes it)
#define WS_RESCUE   WS_XHI
#define WS_ZERO_OFF_BYTES ((size_t)WS_COUNTS * 4)
#define WS_ZERO_BYTES     ((size_t)(8192 + 2097152 + 16) * 4)

// ---- out layout (float-element offsets): quantize, codes, new_embed, new_cs, new_ea
#define OUT_Q   0
#define OUT_C   4194304
#define OUT_NE  4210688
#define OUT_NCS 6307840
#define OUT_NEA 6316032

__device__ inline u16 f2bf_rn(float x) {
    unsigned u = __float_as_uint(x);
    unsigned r = u + 0x7FFFu + ((u >> 16) & 1u);   // round-to-nearest-even
    return (u16)(r >> 16);
}
__device__ inline float bf2f(u16 u) { return __uint_as_float(((unsigned)u) << 16); }
__device__ inline unsigned f2key(float f) {          // order-preserving uint
    unsigned b = __float_as_uint(f);
    return (b & 0x80000000u) ? ~b : (b | 0x80000000u);
}

// ---------------------------------------------------------------------------
// prep: split X,E into bf16 hi/lo; compute esq from fp32 originals.
__global__ __launch_bounds__(256) void prep_kernel(
    const float* __restrict__ X, const float* __restrict__ E,
    u16* __restrict__ Xhi, u16* __restrict__ Xlo,
    u16* __restrict__ Ehi, u16* __restrict__ Elo,
    float* __restrict__ esq)
{
    int row  = blockIdx.x * 4 + (threadIdx.x >> 6);
    int lane = threadIdx.x & 63;
    bool isX = row < M_TOK;
    int r = isX ? row : row - M_TOK;
    const float* src = isX ? X + (size_t)row * DIM : E + (size_t)r * DIM;
    float4 v = ((const float4*)src)[lane];

    ushort4 h, lo;
    {
        u16 hb = f2bf_rn(v.x); h.x = hb; lo.x = f2bf_rn(v.x - bf2f(hb));
        hb = f2bf_rn(v.y); h.y = hb; lo.y = f2bf_rn(v.y - bf2f(hb));
        hb = f2bf_rn(v.z); h.z = hb; lo.z = f2bf_rn(v.z - bf2f(hb));
        hb = f2bf_rn(v.w); h.w = hb; lo.w = f2bf_rn(v.w - bf2f(hb));
    }
    u16* dh = isX ? Xhi : Ehi;
    u16* dl = isX ? Xlo : Elo;
    *(ushort4*)&dh[(size_t)r * DIM + lane * 4] = h;
    *(ushort4*)&dl[(size_t)r * DIM + lane * 4] = lo;

    if (!isX) {
        float s = v.x * v.x + v.y * v.y + v.z * v.z + v.w * v.w;
        #pragma unroll
        for (int o = 1; o < 64; o <<= 1) s += __shfl_xor(s, o, 64);
        if (lane == 0) esq[r] = s;
    }
}

// ---------------------------------------------------------------------------
// mfma_argmin (32x32x16): per 128x128 tile, dot = hi*hi + lo*hi + hi*lo.
// Wave tile 64x64 as 2x2 frags of 32x32, K=16 per MFMA (2 k-steps per BK=32).
// LDS staged via global_load_lds(16B) with XOR chunk swizzle; writer puts
// global chunk g of row r at physical g ^ s(r), s(r)=((r&15)>>1)&3; readers
// apply the same XOR -> every lane gets its true global k-chunk.
// C/D map (m74/m101-verified): col=lane&31, row=(reg&3)+8*(reg>>2)+4*(lane>>5).
__global__ __launch_bounds__(256, 2) void mfma_argmin_kernel(
    const u16* __restrict__ Xhi, const u16* __restrict__ Xlo,
    const u16* __restrict__ Ehi, const u16* __restrict__ Elo,
    const float* __restrict__ esq,
    float* __restrict__ candV, int* __restrict__ candI, float* __restrict__ candS)
{
    __shared__ __align__(16) char tiles[4 * 8192];   // Ahi, Alo, Bhi, Blo
    __shared__ float smB[2][128];
    __shared__ int   smI[2][128];
    __shared__ float smS[2][128];

    const int tid = threadIdx.x;
    const int w = tid >> 6, l = tid & 63;
    const int wy = w >> 1, wx = w & 1;
    const int m0 = blockIdx.x * BM;
    const int n0 = blockIdx.y * BN;

    f32x16 acc[2][2];
    #pragma unroll
    for (int i = 0; i < 2; ++i)
        #pragma unroll
        for (int j = 0; j < 2; ++j) acc[i][j] = (f32x16)0.0f;

    // staging: wave w stages tile w (0=Ahi 1=Alo 2=Bhi 3=Blo)
    const u16* gbase;
    int row0;
    if (w == 0)      { gbase = Xhi; row0 = m0; }
    else if (w == 1) { gbase = Xlo; row0 = m0; }
    else if (w == 2) { gbase = Ehi; row0 = n0; }
    else             { gbase = Elo; row0 = n0; }
    const int swz_c = (l & 3) ^ ((l >> 3) & 3);
    const u16* gsrc0 = gbase + (size_t)(row0 + (l >> 2)) * DIM + swz_c * 8;
    char* ltile = tiles + w * 8192;

    // fragment read addressing (32x32x16: m=lane&31, k=(lane>>5)*8+j)
    const int frow = l & 31, fq2 = l >> 5;
    const int fsw = ((l & 15) >> 1) & 3;                 // s(row mod 16)
    const int pOff0 = ((0 * 2 + fq2) ^ fsw) * 16;        // ks2=0 phys chunk
    const int pOff1 = ((1 * 2 + fq2) ^ fsw) * 16;        // ks2=1 phys chunk
    const int rA0 = (wy * 64 + 0 * 32 + frow) * 64;
    const int rA1 = (wy * 64 + 1 * 32 + frow) * 64;
    const int rB0 = (wx * 64 + 0 * 32 + frow) * 64;
    const int rB1 = (wx * 64 + 1 * 32 + frow) * 64;

    for (int ks = 0; ks < DIM / BK; ++ks) {
        const int k0 = ks * BK;
        __syncthreads();
        #pragma unroll
        for (int i = 0; i < 8; ++i) {
            __builtin_amdgcn_global_load_lds(
                (const __attribute__((address_space(1))) unsigned int*)(gsrc0 + (size_t)i * 16 * DIM + k0),
                (__attribute__((address_space(3))) unsigned int*)(ltile + i * 1024),
                16, 0, 0);
        }
        __syncthreads();

        #pragma unroll
        for (int ks2 = 0; ks2 < 2; ++ks2) {
            const int p = ks2 ? pOff1 : pOff0;
            bf16x8 ah0 = *(const bf16x8*)(tiles + 0 * 8192 + rA0 + p);
            bf16x8 ah1 = *(const bf16x8*)(tiles + 0 * 8192 + rA1 + p);
            bf16x8 al0 = *(const bf16x8*)(tiles + 1 * 8192 + rA0 + p);
            bf16x8 al1 = *(const bf16x8*)(tiles + 1 * 8192 + rA1 + p);
            bf16x8 bh0 = *(const bf16x8*)(tiles + 2 * 8192 + rB0 + p);
            bf16x8 bh1 = *(const bf16x8*)(tiles + 2 * 8192 + rB1 + p);
            bf16x8 bl0 = *(const bf16x8*)(tiles + 3 * 8192 + rB0 + p);
            bf16x8 bl1 = *(const bf16x8*)(tiles + 3 * 8192 + rB1 + p);
            // 4 independent chains of 3 chained MFMAs each
            acc[0][0] = __builtin_amdgcn_mfma_f32_32x32x16_bf16(ah0, bh0, acc[0][0], 0, 0, 0);
            acc[0][1] = __builtin_amdgcn_mfma_f32_32x32x16_bf16(ah0, bh1, acc[0][1], 0, 0, 0);
            acc[1][0] = __builtin_amdgcn_mfma_f32_32x32x16_bf16(ah1, bh0, acc[1][0], 0, 0, 0);
            acc[1][1] = __builtin_amdgcn_mfma_f32_32x32x16_bf16(ah1, bh1, acc[1][1], 0, 0, 0);
            acc[0][0] = __builtin_amdgcn_mfma_f32_32x32x16_bf16(al0, bh0, acc[0][0], 0, 0, 0);
            acc[0][1] = __builtin_amdgcn_mfma_f32_32x32x16_bf16(al0, bh1, acc[0][1], 0, 0, 0);
            acc[1][0] = __builtin_amdgcn_mfma_f32_32x32x16_bf16(al1, bh0, acc[1][0], 0, 0, 0);
            acc[1][1] = __builtin_amdgcn_mfma_f32_32x32x16_bf16(al1, bh1, acc[1][1], 0, 0, 0);
            acc[0][0] = __builtin_amdgcn_mfma_f32_32x32x16_bf16(ah0, bl0, acc[0][0], 0, 0, 0);
            acc[0][1] = __builtin_amdgcn_mfma_f32_32x32x16_bf16(ah0, bl1, acc[0][1], 0, 0, 0);
            acc[1][0] = __builtin_amdgcn_mfma_f32_32x32x16_bf16(ah1, bl0, acc[1][0], 0, 0, 0);
            acc[1][1] = __builtin_amdgcn_mfma_f32_32x32x16_bf16(ah1, bl1, acc[1][1], 0, 0, 0);
        }
    }

    // epilogue: per-row top-2 of val = esq[col] - 2*dot
    const int colA = n0 + wx * 64 + frow;
    const float eq0 = esq[colA];
    const float eq1 = esq[colA + 32];

    #pragma unroll
    for (int mt = 0; mt < 2; ++mt) {
        #pragma unroll
        for (int reg = 0; reg < 16; ++reg) {
            float v0 = fmaf(-2.0f, acc[mt][0][reg], eq0);
            float v1 = fmaf(-2.0f, acc[mt][1][reg], eq1);
            float b, s; int bi;
            if (v1 < v0) { b = v1; bi = colA + 32; s = v0; }
            else         { b = v0; bi = colA;      s = v1; }
            #pragma unroll
            for (int o = 1; o < 32; o <<= 1) {   // stays within 32-lane half
                float ob = __shfl_xor(b, o, 64);
                int   oi = __shfl_xor(bi, o, 64);
                float os = __shfl_xor(s, o, 64);
                bool take = (ob < b) || (ob == b && oi < bi);
                float keep = take ? b : ob;
                b  = take ? ob : b;
                bi = take ? oi : bi;
                s  = fminf(fminf(s, os), keep);
            }
            if (frow == 0) {
                int m_loc = wy * 64 + mt * 32 + (reg & 3) + 8 * (reg >> 2) + 4 * fq2;
                smB[wx][m_loc] = b; smI[wx][m_loc] = bi; smS[wx][m_loc] = s;
            }
        }
    }
    __syncthreads();
    if (tid < 128) {
        float b0 = smB[0][tid], b1 = smB[1][tid];
        int   i0 = smI[0][tid], i1 = smI[1][tid];
        float s0 = smS[0][tid], s1 = smS[1][tid];
        bool take = (b1 < b0);                 // tie -> wave 0 (lower cols)
        float b = take ? b1 : b0;
        int  bi = take ? i1 : i0;
        float s = fminf(fminf(s0, s1), take ? b0 : b1);
        size_t e = (size_t)blockIdx.y * M_TOK + (m0 + tid);
        candV[e] = b; candI[e] = bi; candS[e] = s;
    }
}

// ---------------------------------------------------------------------------
// reduce: fold 64 n-block candidates per row. Batched-8 independent candV
// loads; candS/candI read lazily only for the winning block (true global
// second = min(2nd-min over candV, candS[e*])). Packs (key|idx) u64 into
// rescueBuf; flagged rows get ~0 sentinel for rescue's atomicMin.
__global__ __launch_bounds__(64) void reduce_kernel(
    const float* __restrict__ candV, const int* __restrict__ candI,
    const float* __restrict__ candS,
    int* __restrict__ flagCnt, int* __restrict__ flagRows,
    u64* __restrict__ rescueBuf)
{
    int row = blockIdx.x * 64 + threadIdx.x;
    float best = 3.4e38f, second = 3.4e38f;
    int ebest = 0;
    #pragma unroll
    for (int e0 = 0; e0 < NBLK_N; e0 += 8) {
        float v[8];
        #pragma unroll
        for (int j = 0; j < 8; ++j) v[j] = candV[(size_t)(e0 + j) * M_TOK + row];
        #pragma unroll
        for (int j = 0; j < 8; ++j) {
            if (v[j] < best) { second = best; best = v[j]; ebest = e0 + j; }
            else second = fminf(second, v[j]);
        }
    }
    int bi = candI[(size_t)ebest * M_TOK + row];
    second = fminf(second, candS[(size_t)ebest * M_TOK + row]);
    u64 pk = ((u64)f2key(best) << 32) | (unsigned)bi;
    if (second - best < GAP_EPS) {
        pk = ~0ull;
        int k = atomicAdd(flagCnt, 1);
        flagRows[k] = row;
    }
    rescueBuf[row] = pk;
}

// ---------------------------------------------------------------------------
// rescue: exact fp32 argmin for flagged rows, grid-parallel in the code dim.
__global__ __launch_bounds__(256) void rescue_kernel(
    const float* __restrict__ X, const float* __restrict__ E,
    const float* __restrict__ esq,
    const int* __restrict__ flagCnt, const int* __restrict__ flagRows,
    u64* __restrict__ rescueBuf)
{
    __shared__ float xr[DIM];
    const int nwork = flagCnt[0] * (VOC / 256);
    for (int wk = blockIdx.x; wk < nwork; wk += gridDim.x) {
        int row = flagRows[wk >> 5];
        int c = ((wk & 31) << 8) + threadIdx.x;
        __syncthreads();
        xr[threadIdx.x] = X[(size_t)row * DIM + threadIdx.x];
        __syncthreads();
        const float4* er = (const float4*)(E + (size_t)c * DIM);
        float dot = 0.0f;
        #pragma unroll 8
        for (int k = 0; k < DIM / 4; ++k) {
            float4 e4 = er[k];
            float4 x4 = *(const float4*)&xr[k * 4];
            dot = fmaf(x4.x, e4.x, dot);
            dot = fmaf(x4.y, e4.y, dot);
            dot = fmaf(x4.z, e4.z, dot);
            dot = fmaf(x4.w, e4.w, dot);
        }
        float v = esq[c] - 2.0f * dot;
        u64 pk = ((u64)f2key(v) << 32) | (unsigned)c;
        atomicMin(&rescueBuf[row], pk);
    }
}

// ---------------------------------------------------------------------------
// assign: unpack code, write codes + quantize (STE), scatter counts/sums.
__global__ __launch_bounds__(256) void assign_kernel(
    const float* __restrict__ X, const float* __restrict__ E,
    const u64* __restrict__ rescueBuf,
    float* __restrict__ out_q, float* __restrict__ out_codes,
    float* __restrict__ counts, float* __restrict__ sums)
{
    int t = blockIdx.x * 4 + (threadIdx.x >> 6);
    int lane = threadIdx.x & 63;
    int code = (int)(unsigned)(rescueBuf[t] & 0xFFFFFFFFull);
    if (lane == 0) {
        out_codes[t] = (float)code;
        atomicAdd(&counts[code], 1.0f);
    }
    float4 x = *(const float4*)&X[(size_t)t * DIM + lane * 4];
    float4 e = *(const float4*)&E[(size_t)code * DIM + lane * 4];
    float4 q;
    q.x = x.x + (e.x - x.x);
    q.y = x.y + (e.y - x.y);
    q.z = x.z + (e.z - x.z);
    q.w = x.w + (e.w - x.w);
    *(float4*)&out_q[(size_t)t * DIM + lane * 4] = q;
    float* s = &sums[(size_t)code * DIM + lane * 4];
    atomicAdd(s + 0, x.x);
    atomicAdd(s + 1, x.y);
    atomicAdd(s + 2, x.z);
    atomicAdd(s + 3, x.w);
}

// ---------------------------------------------------------------------------
__global__ __launch_bounds__(256) void finalize_kernel(
    const float* __restrict__ cs, const float* __restrict__ ea,
    const float* __restrict__ counts, const float* __restrict__ sums,
    float* __restrict__ out_embed, float* __restrict__ out_cs,
    float* __restrict__ out_ea)
{
    int vd = blockIdx.x * 256 + threadIdx.x;
    int v = vd >> 8, d = vd & 255;
    float cnt = counts[v];
    float ncs = cs[v] * 0.99f + cnt * 0.01f;
    float cb  = sums[vd] * (1.0f / 2048.0f);
    float nea = ea[vd] * 0.99f + cb * 0.01f;
    out_ea[vd] = nea;
    out_embed[vd] = nea / (ncs + 1e-5f);
    if (d == 0) out_cs[v] = ncs;
}

// ---------------------------------------------------------------------------
extern "C" void kernel_launch(void* const* d_in, const int* in_sizes, int n_in,
                              void* d_out, int out_size, void* d_ws, size_t ws_size,
                              hipStream_t stream)
{
    const float* input     = (const float*)d_in[0];
    const float* embed     = (const float*)d_in[1];
    const float* cluster   = (const float*)d_in[2];
    const float* embed_avg = (const float*)d_in[3];

    float* out = (float*)d_out;
    float* ws  = (float*)d_ws;

    float* esq      = ws + WS_ESQ;
    int*   flagRows = (int*)(ws + WS_FLAGROWS);
    float* candV    = ws + WS_CANDV;
    int*   candI    = (int*)(ws + WS_CANDI);
    float* candS    = ws + WS_CANDS;
    u16*   Xhi      = (u16*)(ws + WS_XHI);
    u16*   Xlo      = (u16*)(ws + WS_XLO);
    u16*   Ehi      = (u16*)(ws + WS_EHI);
    u16*   Elo      = (u16*)(ws + WS_ELO);
    float* counts   = ws + WS_COUNTS;
    float* sums     = ws + WS_SUMS;
    int*   flagCnt  = (int*)(ws + WS_FLAGCNT);
    u64*   rescueBuf= (u64*)(ws + WS_RESCUE);   // aliases dead Xhi

    hipMemsetAsync((char*)d_ws + WS_ZERO_OFF_BYTES, 0, WS_ZERO_BYTES, stream);

    prep_kernel<<<(M_TOK + VOC) / 4, 256, 0, stream>>>(
        input, embed, Xhi, Xlo, Ehi, Elo, esq);

    dim3 g1(M_TOK / BM, VOC / BN);
    mfma_argmin_kernel<<<g1, 256, 0, stream>>>(
        Xhi, Xlo, Ehi, Elo, esq, candV, candI, candS);

    reduce_kernel<<<M_TOK / 64, 64, 0, stream>>>(
        candV, candI, candS, flagCnt, flagRows, rescueBuf);

    rescue_kernel<<<256, 256, 0, stream>>>(
        input, embed, esq, flagCnt, flagRows, rescueBuf);

    assign_kernel<<<M_TOK / 4, 256, 0, stream>>>(
        input, embed, rescueBuf, out + OUT_Q, out + OUT_C, counts, sums);

    finalize_kernel<<<(VOC * DIM) / 256, 256, 0, stream>>>(
        cluster, embed_avg, counts, sums,
        out + OUT_NE, out + OUT_NCS, out + OUT_NEA);
}

// Round 5
// 425.478 us; speedup vs baseline: 1.2197x; 1.2197x over previous
//
#include <hip/hip_runtime.h>
#include <math.h>

// Problem constants (fixed by setup_inputs)
#define M_TOK 16384   // B*T
#define DIM   256     // D (=K)
#define VOC   8192    // V (=N)

// GEMM tiling
#define BM 128
#define BN 128
#define BK 32
#define NBLK_N (VOC / BN)   // 64
#define GAP_EPS 0.01f       // rescue trigger; split-bf16 d2 err ~1e-4 << 0.01

typedef unsigned short u16;
typedef unsigned long long u64;
typedef __attribute__((ext_vector_type(8))) __bf16 bf16x8;
typedef __attribute__((ext_vector_type(4))) float f32x4;

// ---- workspace layout (float-element offsets) ------------------------------
#define WS_ESQ      0                     // [8192]
#define WS_FLAGROWS 24576                 // [16384] int
#define WS_CANDV    40960                 // [64][16384] f32
#define WS_CANDI    1089536               // [64][16384] int
#define WS_CANDS    2138112               // [64][16384] f32
#define WS_XHI      3186688               // [16384*256] bf16 (2097152 f32 slots)
#define WS_XLO      5283840
#define WS_EHI      7380992               // [8192*256] bf16 (1048576 slots)
#define WS_ELO      8429568
#define WS_COUNTS   9478144               // [8192]
#define WS_SUMS     9486336               // [8192*256]
#define WS_FLAGCNT  11583488              // [16] int
// rescueBuf [16384] u64 aliases Xhi (dead after mfma_argmin; reduce writes it)
#define WS_RESCUE   WS_XHI
#define WS_ZERO_OFF_BYTES ((size_t)WS_COUNTS * 4)
#define WS_ZERO_BYTES     ((size_t)(8192 + 2097152 + 16) * 4)

// ---- out layout (float-element offsets): quantize, codes, new_embed, new_cs, new_ea
#define OUT_Q   0
#define OUT_C   4194304
#define OUT_NE  4210688
#define OUT_NCS 6307840
#define OUT_NEA 6316032

__device__ inline u16 f2bf_rn(float x) {
    unsigned u = __float_as_uint(x);
    unsigned r = u + 0x7FFFu + ((u >> 16) & 1u);   // round-to-nearest-even
    return (u16)(r >> 16);
}
__device__ inline float bf2f(u16 u) { return __uint_as_float(((unsigned)u) << 16); }
__device__ inline unsigned f2key(float f) {          // order-preserving uint
    unsigned b = __float_as_uint(f);
    return (b & 0x80000000u) ? ~b : (b | 0x80000000u);
}

// ---------------------------------------------------------------------------
// prep: split X,E into bf16 hi/lo; compute esq from fp32 originals.
__global__ __launch_bounds__(256) void prep_kernel(
    const float* __restrict__ X, const float* __restrict__ E,
    u16* __restrict__ Xhi, u16* __restrict__ Xlo,
    u16* __restrict__ Ehi, u16* __restrict__ Elo,
    float* __restrict__ esq)
{
    int row  = blockIdx.x * 4 + (threadIdx.x >> 6);
    int lane = threadIdx.x & 63;
    bool isX = row < M_TOK;
    int r = isX ? row : row - M_TOK;
    const float* src = isX ? X + (size_t)row * DIM : E + (size_t)r * DIM;
    float4 v = ((const float4*)src)[lane];

    ushort4 h, lo;
    {
        u16 hb = f2bf_rn(v.x); h.x = hb; lo.x = f2bf_rn(v.x - bf2f(hb));
        hb = f2bf_rn(v.y); h.y = hb; lo.y = f2bf_rn(v.y - bf2f(hb));
        hb = f2bf_rn(v.z); h.z = hb; lo.z = f2bf_rn(v.z - bf2f(hb));
        hb = f2bf_rn(v.w); h.w = hb; lo.w = f2bf_rn(v.w - bf2f(hb));
    }
    u16* dh = isX ? Xhi : Ehi;
    u16* dl = isX ? Xlo : Elo;
    *(ushort4*)&dh[(size_t)r * DIM + lane * 4] = h;
    *(ushort4*)&dl[(size_t)r * DIM + lane * 4] = lo;

    if (!isX) {
        float s = v.x * v.x + v.y * v.y + v.z * v.z + v.w * v.w;
        #pragma unroll
        for (int o = 1; o < 64; o <<= 1) s += __shfl_xor(s, o, 64);
        if (lane == 0) esq[r] = s;
    }
}

// ---------------------------------------------------------------------------
// mfma_argmin (16x16x32, round-3 proven: 239us, MfmaUtil 39%, 0 conflicts):
// per 128x128 tile, dot = hi*hi + lo*hi + hi*lo (3 MFMAs per fragment pair),
// epilogue tracks per-row top-2 of (esq[n] - 2*dot).
// LDS staged via global_load_lds(16B) with XOR chunk swizzle (DMA forbids
// padding; swizzle keeps frag ds_read_b128 at <=2-way bank alias = free).
__global__ __launch_bounds__(256, 2) void mfma_argmin_kernel(
    const u16* __restrict__ Xhi, const u16* __restrict__ Xlo,
    const u16* __restrict__ Ehi, const u16* __restrict__ Elo,
    const float* __restrict__ esq,
    float* __restrict__ candV, int* __restrict__ candI, float* __restrict__ candS)
{
    __shared__ __align__(16) char tiles[4 * 8192];   // Ahi, Alo, Bhi, Blo
    __shared__ float smB[2][128];
    __shared__ int   smI[2][128];
    __shared__ float smS[2][128];

    const int tid = threadIdx.x;
    const int w = tid >> 6, l = tid & 63;
    const int wy = w >> 1, wx = w & 1;
    const int m0 = blockIdx.x * BM;
    const int n0 = blockIdx.y * BN;

    f32x4 acc[4][4];
    #pragma unroll
    for (int i = 0; i < 4; ++i)
        #pragma unroll
        for (int j = 0; j < 4; ++j) acc[i][j] = (f32x4)0.0f;

    // staging: wave w stages tile w (0=Ahi 1=Alo 2=Bhi 3=Blo)
    const u16* gbase;
    int row0;
    if (w == 0)      { gbase = Xhi; row0 = m0; }
    else if (w == 1) { gbase = Xlo; row0 = m0; }
    else if (w == 2) { gbase = Ehi; row0 = n0; }
    else             { gbase = Elo; row0 = n0; }
    const int swz_c = (l & 3) ^ ((l >> 3) & 3);
    const u16* gsrc0 = gbase + (size_t)(row0 + (l >> 2)) * DIM + swz_c * 8;
    char* ltile = tiles + w * 8192;

    const int frow = l & 15, fq = l >> 4;
    const int fs = ((fq ^ ((frow >> 1) & 3)) * 16);
    const char* aHiP = tiles + 0 * 8192 + (wy * 64 + frow) * 64 + fs;
    const char* aLoP = tiles + 1 * 8192 + (wy * 64 + frow) * 64 + fs;
    const char* bHiP = tiles + 2 * 8192 + (wx * 64 + frow) * 64 + fs;
    const char* bLoP = tiles + 3 * 8192 + (wx * 64 + frow) * 64 + fs;

    for (int ks = 0; ks < DIM / BK; ++ks) {
        const int k0 = ks * BK;
        __syncthreads();
        #pragma unroll
        for (int i = 0; i < 8; ++i) {
            __builtin_amdgcn_global_load_lds(
                (const __attribute__((address_space(1))) unsigned int*)(gsrc0 + (size_t)i * 16 * DIM + k0),
                (__attribute__((address_space(3))) unsigned int*)(ltile + i * 1024),
                16, 0, 0);
        }
        __syncthreads();

        bf16x8 ah[4], al[4];
        #pragma unroll
        for (int mt = 0; mt < 4; ++mt) {
            ah[mt] = *(const bf16x8*)(aHiP + mt * 1024);
            al[mt] = *(const bf16x8*)(aLoP + mt * 1024);
        }
        #pragma unroll
        for (int nt = 0; nt < 4; ++nt) {
            bf16x8 bh = *(const bf16x8*)(bHiP + nt * 1024);
            bf16x8 bl = *(const bf16x8*)(bLoP + nt * 1024);
            #pragma unroll
            for (int mt = 0; mt < 4; ++mt) {
                acc[mt][nt] = __builtin_amdgcn_mfma_f32_16x16x32_bf16(ah[mt], bh, acc[mt][nt], 0, 0, 0);
                acc[mt][nt] = __builtin_amdgcn_mfma_f32_16x16x32_bf16(al[mt], bh, acc[mt][nt], 0, 0, 0);
                acc[mt][nt] = __builtin_amdgcn_mfma_f32_16x16x32_bf16(ah[mt], bl, acc[mt][nt], 0, 0, 0);
            }
        }
    }

    // epilogue: per-row top-2 argmin of val = esq[n] - 2*dot
    float eq[4];
    #pragma unroll
    for (int nt = 0; nt < 4; ++nt) eq[nt] = esq[n0 + wx * 64 + nt * 16 + frow];

    #pragma unroll
    for (int mt = 0; mt < 4; ++mt) {
        #pragma unroll
        for (int r = 0; r < 4; ++r) {
            float b = 3.4e38f, s = 3.4e38f;
            int bi = 0;
            #pragma unroll
            for (int nt = 0; nt < 4; ++nt) {
                float v = fmaf(-2.0f, acc[mt][nt][r], eq[nt]);
                int col = n0 + wx * 64 + nt * 16 + frow;
                if (v < b) { s = b; b = v; bi = col; }
                else if (v < s) s = v;
            }
            #pragma unroll
            for (int o = 1; o < 16; o <<= 1) {
                float ob = __shfl_xor(b, o, 64);
                int   oi = __shfl_xor(bi, o, 64);
                float os = __shfl_xor(s, o, 64);
                bool take = (ob < b) || (ob == b && oi < bi);
                float keep = take ? b : ob;
                b  = take ? ob : b;
                bi = take ? oi : bi;
                s  = fminf(fminf(s, os), keep);
            }
            if (frow == 0) {
                int m_loc = wy * 64 + mt * 16 + fq * 4 + r;
                smB[wx][m_loc] = b; smI[wx][m_loc] = bi; smS[wx][m_loc] = s;
            }
        }
    }
    __syncthreads();
    if (tid < 128) {
        float b0 = smB[0][tid], b1 = smB[1][tid];
        int   i0 = smI[0][tid], i1 = smI[1][tid];
        float s0 = smS[0][tid], s1 = smS[1][tid];
        bool take = (b1 < b0);                 // tie -> wave 0 (lower cols)
        float b = take ? b1 : b0;
        int  bi = take ? i1 : i0;
        float s = fminf(fminf(s0, s1), take ? b0 : b1);
        size_t e = (size_t)blockIdx.y * M_TOK + (m0 + tid);
        candV[e] = b; candI[e] = bi; candS[e] = s;
    }
}

// ---------------------------------------------------------------------------
// reduce: fold 64 n-block candidates per row. Batched-8 independent candV
// loads; candS/candI read lazily only for the winning block (true global
// second = min(2nd-min over candV, candS[e*])). Packs (key|idx) u64 into
// rescueBuf; flagged rows get ~0 sentinel for rescue's atomicMin.
__global__ __launch_bounds__(64) void reduce_kernel(
    const float* __restrict__ candV, const int* __restrict__ candI,
    const float* __restrict__ candS,
    int* __restrict__ flagCnt, int* __restrict__ flagRows,
    u64* __restrict__ rescueBuf)
{
    int row = blockIdx.x * 64 + threadIdx.x;
    float best = 3.4e38f, second = 3.4e38f;
    int ebest = 0;
    #pragma unroll
    for (int e0 = 0; e0 < NBLK_N; e0 += 8) {
        float v[8];
        #pragma unroll
        for (int j = 0; j < 8; ++j) v[j] = candV[(size_t)(e0 + j) * M_TOK + row];
        #pragma unroll
        for (int j = 0; j < 8; ++j) {
            if (v[j] < best) { second = best; best = v[j]; ebest = e0 + j; }
            else second = fminf(second, v[j]);
        }
    }
    int bi = candI[(size_t)ebest * M_TOK + row];
    second = fminf(second, candS[(size_t)ebest * M_TOK + row]);
    u64 pk = ((u64)f2key(best) << 32) | (unsigned)bi;
    if (second - best < GAP_EPS) {
        pk = ~0ull;
        int k = atomicAdd(flagCnt, 1);
        flagRows[k] = row;
    }
    rescueBuf[row] = pk;
}

// ---------------------------------------------------------------------------
// rescue: exact fp32 argmin for flagged rows, grid-parallel in the code dim.
// Work item = (flagged row, 256-code chunk); winner via u64 atomicMin on
// (sortable-float << 32 | code) -> lowest index on ties.
__global__ __launch_bounds__(256) void rescue_kernel(
    const float* __restrict__ X, const float* __restrict__ E,
    const float* __restrict__ esq,
    const int* __restrict__ flagCnt, const int* __restrict__ flagRows,
    u64* __restrict__ rescueBuf)
{
    __shared__ float xr[DIM];
    const int nwork = flagCnt[0] * (VOC / 256);
    for (int wk = blockIdx.x; wk < nwork; wk += gridDim.x) {
        int row = flagRows[wk >> 5];
        int c = ((wk & 31) << 8) + threadIdx.x;
        __syncthreads();
        xr[threadIdx.x] = X[(size_t)row * DIM + threadIdx.x];
        __syncthreads();
        const float4* er = (const float4*)(E + (size_t)c * DIM);
        float dot = 0.0f;
        #pragma unroll 8
        for (int k = 0; k < DIM / 4; ++k) {
            float4 e4 = er[k];
            float4 x4 = *(const float4*)&xr[k * 4];
            dot = fmaf(x4.x, e4.x, dot);
            dot = fmaf(x4.y, e4.y, dot);
            dot = fmaf(x4.z, e4.z, dot);
            dot = fmaf(x4.w, e4.w, dot);
        }
        float v = esq[c] - 2.0f * dot;
        u64 pk = ((u64)f2key(v) << 32) | (unsigned)c;
        atomicMin(&rescueBuf[row], pk);
    }
}

// ---------------------------------------------------------------------------
// assign: unpack code, write codes + quantize (STE), scatter counts/sums.
__global__ __launch_bounds__(256) void assign_kernel(
    const float* __restrict__ X, const float* __restrict__ E,
    const u64* __restrict__ rescueBuf,
    float* __restrict__ out_q, float* __restrict__ out_codes,
    float* __restrict__ counts, float* __restrict__ sums)
{
    int t = blockIdx.x * 4 + (threadIdx.x >> 6);
    int lane = threadIdx.x & 63;
    int code = (int)(unsigned)(rescueBuf[t] & 0xFFFFFFFFull);
    if (lane == 0) {
        out_codes[t] = (float)code;
        atomicAdd(&counts[code], 1.0f);
    }
    float4 x = *(const float4*)&X[(size_t)t * DIM + lane * 4];
    float4 e = *(const float4*)&E[(size_t)code * DIM + lane * 4];
    float4 q;
    q.x = x.x + (e.x - x.x);
    q.y = x.y + (e.y - x.y);
    q.z = x.z + (e.z - x.z);
    q.w = x.w + (e.w - x.w);
    *(float4*)&out_q[(size_t)t * DIM + lane * 4] = q;
    float* s = &sums[(size_t)code * DIM + lane * 4];
    atomicAdd(s + 0, x.x);
    atomicAdd(s + 1, x.y);
    atomicAdd(s + 2, x.z);
    atomicAdd(s + 3, x.w);
}

// ---------------------------------------------------------------------------
__global__ __launch_bounds__(256) void finalize_kernel(
    const float* __restrict__ cs, const float* __restrict__ ea,
    const float* __restrict__ counts, const float* __restrict__ sums,
    float* __restrict__ out_embed, float* __restrict__ out_cs,
    float* __restrict__ out_ea)
{
    int vd = blockIdx.x * 256 + threadIdx.x;
    int v = vd >> 8, d = vd & 255;
    float cnt = counts[v];
    float ncs = cs[v] * 0.99f + cnt * 0.01f;
    float cb  = sums[vd] * (1.0f / 2048.0f);
    float nea = ea[vd] * 0.99f + cb * 0.01f;
    out_ea[vd] = nea;
    out_embed[vd] = nea / (ncs + 1e-5f);
    if (d == 0) out_cs[v] = ncs;
}

// ---------------------------------------------------------------------------
extern "C" void kernel_launch(void* const* d_in, const int* in_sizes, int n_in,
                              void* d_out, int out_size, void* d_ws, size_t ws_size,
                              hipStream_t stream)
{
    const float* input     = (const float*)d_in[0];
    const float* embed     = (const float*)d_in[1];
    const float* cluster   = (const float*)d_in[2];
    const float* embed_avg = (const float*)d_in[3];

    float* out = (float*)d_out;
    float* ws  = (float*)d_ws;

    float* esq      = ws + WS_ESQ;
    int*   flagRows = (int*)(ws + WS_FLAGROWS);
    float* candV    = ws + WS_CANDV;
    int*   candI    = (int*)(ws + WS_CANDI);
    float* candS    = ws + WS_CANDS;
    u16*   Xhi      = (u16*)(ws + WS_XHI);
    u16*   Xlo      = (u16*)(ws + WS_XLO);
    u16*   Ehi      = (u16*)(ws + WS_EHI);
    u16*   Elo      = (u16*)(ws + WS_ELO);
    float* counts   = ws + WS_COUNTS;
    float* sums     = ws + WS_SUMS;
    int*   flagCnt  = (int*)(ws + WS_FLAGCNT);
    u64*   rescueBuf= (u64*)(ws + WS_RESCUE);   // aliases dead Xhi

    hipMemsetAsync((char*)d_ws + WS_ZERO_OFF_BYTES, 0, WS_ZERO_BYTES, stream);

    prep_kernel<<<(M_TOK + VOC) / 4, 256, 0, stream>>>(
        input, embed, Xhi, Xlo, Ehi, Elo, esq);

    dim3 g1(M_TOK / BM, VOC / BN);
    mfma_argmin_kernel<<<g1, 256, 0, stream>>>(
        Xhi, Xlo, Ehi, Elo, esq, candV, candI, candS);

    reduce_kernel<<<M_TOK / 64, 64, 0, stream>>>(
        candV, candI, candS, flagCnt, flagRows, rescueBuf);

    rescue_kernel<<<256, 256, 0, stream>>>(
        input, embed, esq, flagCnt, flagRows, rescueBuf);

    assign_kernel<<<M_TOK / 4, 256, 0, stream>>>(
        input, embed, rescueBuf, out + OUT_Q, out + OUT_C, counts, sums);

    finalize_kernel<<<(VOC * DIM) / 256, 256, 0, stream>>>(
        cluster, embed_avg, counts, sums,
        out + OUT_NE, out + OUT_NCS, out + OUT_NEA);
}